// Round 1
// baseline (970.812 us; speedup 1.0000x reference)
//
#include <hip/hip_runtime.h>
#include <cstdint>
#include <cstddef>

// Problem constants (match reference)
#define BB 256
#define TT 512
#define KK 128
#define START_TAG 126
#define STOP_TAG 127
#define NEGV (-10000.0f)

// ---------------------------------------------------------------------------
// Main kernel: one block per batch item, 256 threads.
//   threads [0,128)  : CRF forward algorithm (log Z) via E=exp(trans) trick
//   threads [128,256): Viterbi forward (exact max/argmax, bitwise == ref)
// Both roles execute exactly 2 __syncthreads per time step.
// ---------------------------------------------------------------------------
__global__ __launch_bounds__(256, 1) void crf_main(
    const float* __restrict__ feats,   // [B,T,K]
    const float* __restrict__ trans,   // [K,K]  trans[to][from]
    float* __restrict__ logz,          // [B]    (ws)
    float* __restrict__ pscore,        // [B]    (d_out + 1)
    int* __restrict__ lasttag,         // [B]    (ws)
    uint8_t* __restrict__ bptr)        // [B,T,K] backpointers (ws)
{
  const int b    = blockIdx.x;
  const int tid  = threadIdx.x;
  const bool is_fwd = (tid < KK);
  const int to   = tid & (KK - 1);
  const int lane = tid & 63;
  const int wv   = tid >> 6;            // 0,1 fwd waves; 2,3 vit waves

  __shared__ __align__(16) float P[KK];        // fwd message exp(alpha - mA)
  __shared__ __align__(16) float av[2][KK];    // viterbi alpha double buffer
  __shared__ float redm[2];                    // fwd cross-wave max
  __shared__ float reds[2];                    // fwd cross-wave sum
  __shared__ float redmv[2];                   // vit cross-wave max
  __shared__ int   rediv[2];                   // vit cross-wave argmax

  // Per-thread row of transitions: E=exp(trans[to][:]) for fwd, raw for vit.
  float R[KK];
  {
    const float4* trow = reinterpret_cast<const float4*>(trans + (size_t)to * KK);
#pragma unroll
    for (int c = 0; c < KK / 4; ++c) {
      float4 v = trow[c];
      if (is_fwd) {
        R[4*c+0] = expf(v.x); R[4*c+1] = expf(v.y);
        R[4*c+2] = expf(v.z); R[4*c+3] = expf(v.w);
      } else {
        R[4*c+0] = v.x; R[4*c+1] = v.y; R[4*c+2] = v.z; R[4*c+3] = v.w;
      }
    }
  }

  // init state
  float mA = 0.0f;                       // running max of forward alpha
  float a;                               // this thread's alpha (absolute)
  if (is_fwd) {
    P[to] = (to == START_TAG) ? 1.0f : 0.0f;   // exp(init - 0)
    a = (to == START_TAG) ? 0.0f : NEGV;
  } else {
    av[0][to] = (to == START_TAG) ? 0.0f : NEGV;
  }
  __syncthreads();

  const float* fb = feats + ((size_t)b * TT) * KK + to;
  uint8_t* bp = bptr + ((size_t)b * TT) * KK + to;
  int cur = 0;

  for (int t = 0; t < TT; ++t) {
    if (is_fwd) {
      // alpha_new[to] = mA + log( sum_f E[to][f] * P[f] ) + feat
      float s0 = 0.f, s1 = 0.f, s2 = 0.f, s3 = 0.f;
      const float4* P4 = reinterpret_cast<const float4*>(P);
#pragma unroll
      for (int c = 0; c < KK / 4; ++c) {
        float4 p = P4[c];                 // wave-broadcast LDS read
        s0 = fmaf(R[4*c+0], p.x, s0);
        s1 = fmaf(R[4*c+1], p.y, s1);
        s2 = fmaf(R[4*c+2], p.z, s2);
        s3 = fmaf(R[4*c+3], p.w, s3);
      }
      float s = (s0 + s1) + (s2 + s3);
      a = mA + logf(s) + fb[(size_t)t * KK];   // to==START: log(0)=-inf, safe
      float m = a;
#pragma unroll
      for (int off = 32; off >= 1; off >>= 1) m = fmaxf(m, __shfl_xor(m, off, 64));
      if (lane == 0) redm[wv] = m;
    } else {
      // Viterbi: exact max/argmax, first-max tie rule (strict >)
      float m = -__builtin_huge_valf();
      int idx = 0;
      const float4* A4 = reinterpret_cast<const float4*>(av[cur]);
#pragma unroll
      for (int c = 0; c < KK / 4; ++c) {
        float4 p = A4[c];                 // wave-broadcast LDS read
        float v0 = p.x + R[4*c+0]; if (v0 > m) { m = v0; idx = 4*c+0; }
        float v1 = p.y + R[4*c+1]; if (v1 > m) { m = v1; idx = 4*c+1; }
        float v2 = p.z + R[4*c+2]; if (v2 > m) { m = v2; idx = 4*c+2; }
        float v3 = p.w + R[4*c+3]; if (v3 > m) { m = v3; idx = 4*c+3; }
      }
      a = m + fb[(size_t)t * KK];
      bp[(size_t)t * KK] = (uint8_t)idx;
      av[cur ^ 1][to] = a;
    }
    __syncthreads();
    if (is_fwd) {
      float m = fmaxf(redm[0], redm[1]);
      P[to] = expf(a - m);               // a==-inf -> 0, safe
      mA = m;
    }
    __syncthreads();
    cur ^= 1;
  }

  // ---- terminal reductions ----
  float term = a + trans[(size_t)STOP_TAG * KK + to];
  if (is_fwd) {
    float m = term;
#pragma unroll
    for (int off = 32; off >= 1; off >>= 1) m = fmaxf(m, __shfl_xor(m, off, 64));
    if (lane == 0) redm[wv] = m;
    __syncthreads();
    m = fmaxf(redm[0], redm[1]);
    float e = expf(term - m);
#pragma unroll
    for (int off = 32; off >= 1; off >>= 1) e += __shfl_xor(e, off, 64);
    if (lane == 0) reds[wv] = e;
    __syncthreads();
    if (tid == 0) logz[b] = m + logf(reds[0] + reds[1]);
  } else {
    float m = term;
    int idx = to;
#pragma unroll
    for (int off = 1; off <= 32; off <<= 1) {
      float om = __shfl_xor(m, off, 64);
      int   oi = __shfl_xor(idx, off, 64);
      if (om > m || (om == m && oi < idx)) { m = om; idx = oi; }
    }
    if (lane == 0) { redmv[wv - 2] = m; rediv[wv - 2] = idx; }
    __syncthreads();
    if (to == 0) {
      float m0 = redmv[0], m1 = redmv[1];
      int   i0 = rediv[0], i1 = rediv[1];
      if (m1 > m0 || (m1 == m0 && i1 < i0)) { m0 = m1; i0 = i1; }
      pscore[b]  = m0;
      lasttag[b] = i0;
    }
    __syncthreads();   // match fwd's second barrier
  }
}

// ---------------------------------------------------------------------------
// Backtrace: one block per b. Stage 64KB of backpointers into LDS in two
// 32KB halves; single thread walks the chain in LDS (no dependent global
// loads), writing pred as float.
// ---------------------------------------------------------------------------
__global__ __launch_bounds__(256) void backtrace_kernel(
    const uint8_t* __restrict__ bptr, const int* __restrict__ lasttag,
    float* __restrict__ pred)
{
  const int b = blockIdx.x;
  const int tid = threadIdx.x;
  __shared__ __align__(16) uint8_t lb[(TT / 2) * KK];   // 32 KB
  __shared__ int tagcarry;
  if (tid == 0) tagcarry = lasttag[b];

  for (int half = 1; half >= 0; --half) {
    __syncthreads();   // previous half's walk done; tagcarry visible
    const float4* src = reinterpret_cast<const float4*>(
        bptr + ((size_t)b * TT + (size_t)half * (TT / 2)) * KK);
    float4* dst = reinterpret_cast<float4*>(lb);
    for (int i = tid; i < (TT / 2) * KK / 16; i += 256) dst[i] = src[i];
    __syncthreads();
    if (tid == 0) {
      int tag = tagcarry;
      for (int t = TT / 2 - 1; t >= 0; --t) {
        int gt = half * (TT / 2) + t;
        pred[(size_t)b * TT + gt] = (float)tag;
        tag = lb[t * KK + tag];
      }
      tagcarry = tag;
    }
  }
}

// ---------------------------------------------------------------------------
// Gold path score per b: gb[b] = logz[b] - score_sentence(b)
// ---------------------------------------------------------------------------
__global__ __launch_bounds__(64) void gold_kernel(
    const float* __restrict__ feats, const int* __restrict__ tags,
    const float* __restrict__ trans, const float* __restrict__ logz,
    float* __restrict__ gb)
{
  const int b = blockIdx.x;
  const int lane = threadIdx.x;         // 0..63, one wave
  const int* tg = tags + (size_t)b * TT;
  const float* fb = feats + ((size_t)b * TT) * KK;
  float g = 0.0f;
#pragma unroll
  for (int k = 0; k < TT / 64; ++k) {
    int t = lane * (TT / 64) + k;
    int ct = tg[t];
    int pv = (t == 0) ? START_TAG : tg[t - 1];
    g += trans[ct * KK + pv] + fb[(size_t)t * KK + ct];
  }
  if (lane == 63) g += trans[STOP_TAG * KK + tg[TT - 1]];
#pragma unroll
  for (int off = 1; off <= 32; off <<= 1) g += __shfl_xor(g, off, 64);
  if (lane == 0) gb[b] = logz[b] - g;
}

__global__ __launch_bounds__(256) void loss_reduce(
    const float* __restrict__ gb, float* __restrict__ out)
{
  const int tid = threadIdx.x;
  const int lane = tid & 63, wv = tid >> 6;
  float v = gb[tid];
#pragma unroll
  for (int off = 1; off <= 32; off <<= 1) v += __shfl_xor(v, off, 64);
  __shared__ float red[4];
  if (lane == 0) red[wv] = v;
  __syncthreads();
  if (tid == 0) out[0] = (red[0] + red[1] + red[2] + red[3]) / (float)(BB * TT);
}

// ---------------------------------------------------------------------------
extern "C" void kernel_launch(void* const* d_in, const int* in_sizes, int n_in,
                              void* d_out, int out_size, void* d_ws, size_t ws_size,
                              hipStream_t stream) {
  const float* feats = (const float*)d_in[0];   // [256,512,128] f32
  const int*   tags  = (const int*)d_in[1];     // [256,512] i32
  const float* trans = (const float*)d_in[2];   // [128,128] f32

  float* out    = (float*)d_out;
  float* loss   = out;                 // [1]
  float* pscore = out + 1;             // [B]
  float* pred   = out + 1 + BB;        // [B*T] tags as floats

  // workspace layout: bptr (16 MB) | logz (1 KB) | lasttag (1 KB) | gb (1 KB)
  uint8_t* bptr    = (uint8_t*)d_ws;
  char*    wsend   = (char*)d_ws + (size_t)BB * TT * KK;
  float*   logz    = (float*)(wsend);
  int*     lasttag = (int*)(wsend + BB * sizeof(float));
  float*   gb      = (float*)(wsend + BB * sizeof(float) + BB * sizeof(int));
  (void)ws_size; (void)in_sizes; (void)n_in; (void)out_size;

  crf_main<<<BB, 256, 0, stream>>>(feats, trans, logz, pscore, lasttag, bptr);
  backtrace_kernel<<<BB, 256, 0, stream>>>(bptr, lasttag, pred);
  gold_kernel<<<BB, 64, 0, stream>>>(feats, tags, trans, logz, gb);
  loss_reduce<<<1, 256, 0, stream>>>(gb, loss);
}

// Round 2
// 506.611 us; speedup vs baseline: 1.9163x; 1.9163x over previous
//
#include <hip/hip_runtime.h>
#include <cstdint>
#include <cstddef>

#define BB 256
#define TT 512
#define KK 128
#define START_TAG 126
#define STOP_TAG 127
#define NEGV (-10000.0f)
#define NINF (-__builtin_huge_valf())

// ---- DPP helpers (VALU-pipe cross-lane, no LDS traffic) --------------------
template<int CTRL>
__device__ __forceinline__ float dppf(float v, float old) {
  return __int_as_float(__builtin_amdgcn_update_dpp(
      __float_as_int(old), __float_as_int(v), CTRL, 0xf, 0xf, false));
}
template<int CTRL>
__device__ __forceinline__ int dppi(int v, int old) {
  return __builtin_amdgcn_update_dpp(old, v, CTRL, 0xf, 0xf, false);
}
// canonical wave64 max reduction; result valid in lane 63
__device__ __forceinline__ float wave_max63(float x) {
  x = fmaxf(x, dppf<0x111>(x, NINF));  // row_shr:1
  x = fmaxf(x, dppf<0x112>(x, NINF));  // row_shr:2
  x = fmaxf(x, dppf<0x114>(x, NINF));  // row_shr:4
  x = fmaxf(x, dppf<0x118>(x, NINF));  // row_shr:8
  x = fmaxf(x, dppf<0x142>(x, NINF));  // row_bcast:15
  x = fmaxf(x, dppf<0x143>(x, NINF));  // row_bcast:31
  return x;
}
// padded LDS address: 32-float sections padded to 36 (bank-spread across h)
__device__ __forceinline__ int paddr(int i) { return (i >> 5) * 36 + (i & 31); }

// ---------------------------------------------------------------------------
// crf_main: one block per batch item, 768 threads (12 waves).
//   tid [0,256)  : forward alg, 2 threads per 'to' (h=tid&1 -> 64 'from' each)
//   tid [256,768): Viterbi, 4 threads per 'to' (h -> 32 'from' each)
// ONE barrier per step; P published with one-step-stale block max (exact
// algebra, bounded exponent). Viterbi max/argmax bitwise-exact vs jnp.
// ---------------------------------------------------------------------------
__global__ __launch_bounds__(768) void crf_main(
    const float* __restrict__ feats, const float* __restrict__ trans,
    float* __restrict__ logz, float* __restrict__ pscore,
    int* __restrict__ lasttag, uint8_t* __restrict__ bptr)
{
  const int b = blockIdx.x;
  const int tid = threadIdx.x;
  const bool is_fwd = tid < 256;
  const int lane = tid & 63;

  __shared__ __align__(16) float P[2][144];     // fwd message exp(a - M)
  __shared__ __align__(16) float AV[2][144];    // viterbi alpha
  __shared__ __align__(16) float redmF[2][4];   // per-fwd-wave max (dbuf)
  __shared__ float reds[4];
  __shared__ float vitm[8];
  __shared__ int   viti[8];

  int myto, h;
  if (is_fwd) { myto = tid >> 1; h = tid & 1; }
  else { int q = tid - 256; myto = q >> 2; h = q & 3; }

  // per-thread transition slice: E=exp(trans) for fwd, raw for vit
  float R[64];
  if (is_fwd) {
    const float4* tr = (const float4*)(trans + (size_t)myto * KK + h * 64);
#pragma unroll
    for (int c = 0; c < 16; ++c) {
      float4 v = tr[c];
      R[4*c+0]=expf(v.x); R[4*c+1]=expf(v.y); R[4*c+2]=expf(v.z); R[4*c+3]=expf(v.w);
    }
  } else {
    const float4* tr = (const float4*)(trans + (size_t)myto * KK + h * 32);
#pragma unroll
    for (int c = 0; c < 8; ++c) {
      float4 v = tr[c];
      R[4*c+0]=v.x; R[4*c+1]=v.y; R[4*c+2]=v.z; R[4*c+3]=v.w;
    }
  }

  if (is_fwd) { if (h == 0) P[0][paddr(myto)] = (myto==START_TAG)?1.0f:0.0f; }
  else        { if (h == 0) AV[0][paddr(myto)] = (myto==START_TAG)?0.0f:NEGV; }
  if (tid < 4) redmF[1][tid] = 0.0f;   // M_{-1} = max(init alpha) = 0
  __syncthreads();

  const float* fb = feats + (size_t)b * TT * KK + myto;
  uint8_t* bp = bptr + (size_t)b * TT * KK + myto;

  float fcur = fb[0];          // prefetched feat for step t
  float Mprev = 0.0f;          // scale of the P we consume (M_{t-2})
  float aCarry = 0.0f;
  int cur = 0;

  for (int t = 0; t < TT; ++t) {
    const int tn = (t + 1 < TT) ? t + 1 : t;
    float fnext = fb[(size_t)tn * KK];          // issue early, hide latency
    const int rd = (t + 1) & 1, wr = t & 1;

    if (is_fwd) {
      float4 rv = *(const float4*)&redmF[rd][0];
      float M1 = fmaxf(fmaxf(rv.x, rv.y), fmaxf(rv.z, rv.w));   // M_{t-1}
      const float* Pc = &P[cur][0];
      const int base = h * 72;
      float s0=0.f, s1=0.f, s2=0.f, s3=0.f;
#pragma unroll
      for (int c = 0; c < 16; ++c) {
        float4 p = *(const float4*)&Pc[base + (c>>3)*36 + (c&7)*4];
        s0 = fmaf(R[4*c+0], p.x, s0);
        s1 = fmaf(R[4*c+1], p.y, s1);
        s2 = fmaf(R[4*c+2], p.z, s2);
        s3 = fmaf(R[4*c+3], p.w, s3);
      }
      float s = (s0 + s1) + (s2 + s3);
      s = s + dppf<0xB1>(s, s);                 // pair merge (exact, commutative)
      float a = Mprev + logf(s) + fcur;         // to==START: log(0)=-inf, safe
      float wm = wave_max63(a);
      if (lane == 63) redmF[wr][tid >> 6] = wm;
      float pv = expf(a - M1);                  // publish with stale max
      if (h == 0) P[cur ^ 1][paddr(myto)] = pv;
      Mprev = M1;
      aCarry = a;
    } else {
      const float* Ac = &AV[cur][0];
      const int base = h * 36;
      const int fb0 = h * 32;
      float4 p0 = *(const float4*)&Ac[base];
      float m0 = p0.x + R[0], m1 = p0.y + R[1], m2 = p0.z + R[2], m3 = p0.w + R[3];
      int i0 = fb0, i1 = fb0+1, i2 = fb0+2, i3 = fb0+3;
#pragma unroll
      for (int c = 1; c < 8; ++c) {             // ascending f within each chain
        float4 p = *(const float4*)&Ac[base + c*4];
        float v0 = p.x + R[4*c+0]; if (v0 > m0) { m0 = v0; i0 = fb0+4*c+0; }
        float v1 = p.y + R[4*c+1]; if (v1 > m1) { m1 = v1; i1 = fb0+4*c+1; }
        float v2 = p.z + R[4*c+2]; if (v2 > m2) { m2 = v2; i2 = fb0+4*c+2; }
        float v3 = p.w + R[4*c+3]; if (v3 > m3) { m3 = v3; i3 = fb0+4*c+3; }
      }
      float m = m0; int i = i0;                 // exact first-index tie rule
      if (m1 > m || (m1 == m && i1 < i)) { m = m1; i = i1; }
      if (m2 > m || (m2 == m && i2 < i)) { m = m2; i = i2; }
      if (m3 > m || (m3 == m && i3 < i)) { m = m3; i = i3; }
      { float mo = dppf<0xB1>(m, m); int io = dppi<0xB1>(i, i);
        if (mo > m || (mo == m && io < i)) { m = mo; i = io; } }
      { float mo = dppf<0x4E>(m, m); int io = dppi<0x4E>(i, i);
        if (mo > m || (mo == m && io < i)) { m = mo; i = io; } }
      float a = m + fcur;
      if (h == 0) { AV[cur ^ 1][paddr(myto)] = a; bp[(size_t)t * KK] = (uint8_t)i; }
      aCarry = a;
    }
    __syncthreads();                            // single barrier per step
    cur ^= 1;
    fcur = fnext;
  }

  // ---- terminal reductions ----
  float tstop = trans[(size_t)STOP_TAG * KK + myto];
  float term = aCarry + tstop;
  float M = 0.0f;
  if (is_fwd) {
    float wm = wave_max63(term);
    if (lane == 63) redmF[0][tid >> 6] = wm;
  } else {
    float m = term; int i = myto;
#pragma unroll
    for (int off = 1; off < 64; off <<= 1) {
      float mo = __shfl_xor(m, off, 64);
      int   io = __shfl_xor(i, off, 64);
      if (mo > m || (mo == m && io < i)) { m = mo; i = io; }
    }
    if (lane == 0) { vitm[(tid>>6)-4] = m; viti[(tid>>6)-4] = i; }
  }
  __syncthreads();
  if (is_fwd) {
    float4 rv = *(const float4*)&redmF[0][0];
    M = fmaxf(fmaxf(rv.x, rv.y), fmaxf(rv.z, rv.w));
    float e = expf(term - M);
#pragma unroll
    for (int off = 1; off < 64; off <<= 1) e += __shfl_xor(e, off, 64);
    if (lane == 0) reds[tid >> 6] = e;
  } else if (tid == 256) {
    float m = vitm[0]; int i = viti[0];
#pragma unroll
    for (int w = 1; w < 8; ++w)
      if (vitm[w] > m || (vitm[w] == m && viti[w] < i)) { m = vitm[w]; i = viti[w]; }
    pscore[b] = m; lasttag[b] = i;
  }
  __syncthreads();
  if (tid == 0) logz[b] = M + logf(reds[0] + reds[1] + reds[2] + reds[3]);
}

// ---------------------------------------------------------------------------
// Backtrace: one block per b; stage bptr into LDS in 32KB halves, walk in LDS.
// ---------------------------------------------------------------------------
__global__ __launch_bounds__(256) void backtrace_kernel(
    const uint8_t* __restrict__ bptr, const int* __restrict__ lasttag,
    float* __restrict__ pred)
{
  const int b = blockIdx.x;
  const int tid = threadIdx.x;
  __shared__ __align__(16) uint8_t lb[(TT / 2) * KK];   // 32 KB
  __shared__ int tagcarry;
  if (tid == 0) tagcarry = lasttag[b];

  for (int half = 1; half >= 0; --half) {
    __syncthreads();
    const float4* src = reinterpret_cast<const float4*>(
        bptr + ((size_t)b * TT + (size_t)half * (TT / 2)) * KK);
    float4* dst = reinterpret_cast<float4*>(lb);
    for (int i = tid; i < (TT / 2) * KK / 16; i += 256) dst[i] = src[i];
    __syncthreads();
    if (tid == 0) {
      int tag = tagcarry;
      for (int t = TT / 2 - 1; t >= 0; --t) {
        int gt = half * (TT / 2) + t;
        pred[(size_t)b * TT + gt] = (float)tag;
        tag = lb[t * KK + tag];
      }
      tagcarry = tag;
    }
  }
}

// ---------------------------------------------------------------------------
__global__ __launch_bounds__(64) void gold_kernel(
    const float* __restrict__ feats, const int* __restrict__ tags,
    const float* __restrict__ trans, const float* __restrict__ logz,
    float* __restrict__ gb)
{
  const int b = blockIdx.x;
  const int lane = threadIdx.x;
  const int* tg = tags + (size_t)b * TT;
  const float* fb = feats + (size_t)b * TT * KK;
  float g = 0.0f;
#pragma unroll
  for (int k = 0; k < TT / 64; ++k) {
    int t = lane * (TT / 64) + k;
    int ct = tg[t];
    int pv = (t == 0) ? START_TAG : tg[t - 1];
    g += trans[ct * KK + pv] + fb[(size_t)t * KK + ct];
  }
  if (lane == 63) g += trans[STOP_TAG * KK + tg[TT - 1]];
#pragma unroll
  for (int off = 1; off <= 32; off <<= 1) g += __shfl_xor(g, off, 64);
  if (lane == 0) gb[b] = logz[b] - g;
}

__global__ __launch_bounds__(256) void loss_reduce(
    const float* __restrict__ gb, float* __restrict__ out)
{
  const int tid = threadIdx.x;
  const int lane = tid & 63, wv = tid >> 6;
  float v = gb[tid];
#pragma unroll
  for (int off = 1; off <= 32; off <<= 1) v += __shfl_xor(v, off, 64);
  __shared__ float red[4];
  if (lane == 0) red[wv] = v;
  __syncthreads();
  if (tid == 0) out[0] = (red[0] + red[1] + red[2] + red[3]) / (float)(BB * TT);
}

// ---------------------------------------------------------------------------
extern "C" void kernel_launch(void* const* d_in, const int* in_sizes, int n_in,
                              void* d_out, int out_size, void* d_ws, size_t ws_size,
                              hipStream_t stream) {
  const float* feats = (const float*)d_in[0];
  const int*   tags  = (const int*)d_in[1];
  const float* trans = (const float*)d_in[2];

  float* out    = (float*)d_out;
  float* loss   = out;
  float* pscore = out + 1;
  float* pred   = out + 1 + BB;

  uint8_t* bptr    = (uint8_t*)d_ws;
  char*    wsend   = (char*)d_ws + (size_t)BB * TT * KK;
  float*   logz    = (float*)(wsend);
  int*     lasttag = (int*)(wsend + BB * sizeof(float));
  float*   gb      = (float*)(wsend + BB * sizeof(float) + BB * sizeof(int));
  (void)ws_size; (void)in_sizes; (void)n_in; (void)out_size;

  crf_main<<<BB, 768, 0, stream>>>(feats, trans, logz, pscore, lasttag, bptr);
  backtrace_kernel<<<BB, 256, 0, stream>>>(bptr, lasttag, pred);
  gold_kernel<<<BB, 64, 0, stream>>>(feats, tags, trans, logz, gb);
  loss_reduce<<<1, 256, 0, stream>>>(gb, loss);
}

// Round 3
// 425.952 us; speedup vs baseline: 2.2792x; 1.1894x over previous
//
#include <hip/hip_runtime.h>
#include <cstdint>
#include <cstddef>

#define BB 256
#define TT 512
#define KK 128
#define START_TAG 126
#define STOP_TAG 127
#define NEGV (-10000.0f)
#define NINF (-__builtin_huge_valf())

// ---- DPP helpers (VALU-pipe cross-lane, no LDS traffic) --------------------
template<int CTRL>
__device__ __forceinline__ float dppf(float v, float old) {
  return __int_as_float(__builtin_amdgcn_update_dpp(
      __float_as_int(old), __float_as_int(v), CTRL, 0xf, 0xf, false));
}
template<int CTRL>
__device__ __forceinline__ int dppi(int v, int old) {
  return __builtin_amdgcn_update_dpp(old, v, CTRL, 0xf, 0xf, false);
}
// canonical wave64 max reduction; result valid in lane 63
__device__ __forceinline__ float wave_max63(float x) {
  x = fmaxf(x, dppf<0x111>(x, NINF));  // row_shr:1
  x = fmaxf(x, dppf<0x112>(x, NINF));  // row_shr:2
  x = fmaxf(x, dppf<0x114>(x, NINF));  // row_shr:4
  x = fmaxf(x, dppf<0x118>(x, NINF));  // row_shr:8
  x = fmaxf(x, dppf<0x142>(x, NINF));  // row_bcast:15
  x = fmaxf(x, dppf<0x143>(x, NINF));  // row_bcast:31
  return x;
}
__device__ __forceinline__ int paddr(int i) { return (i >> 5) * 36 + (i & 31); }

// ---------------------------------------------------------------------------
// crf_main: one block per batch item, 768 threads (12 waves).
//   tid [0,256)  : forward alg, 2 threads per 'to' (h -> 64 'from' each)
//   tid [256,768): Viterbi, 4 threads per 'to' (h -> 32 'from' each)
// CHEAP: Viterbi stores exact alpha rows (no argmax); backtrace recomputes.
// !CHEAP: R2-proven bptr path (ws too small fallback).
// ---------------------------------------------------------------------------
template<bool CHEAP>
__global__ __launch_bounds__(768) void crf_main(
    const float* __restrict__ feats, const float* __restrict__ trans,
    float* __restrict__ logz, float* __restrict__ pscore,
    int* __restrict__ lasttag, uint8_t* __restrict__ bptr,
    float* __restrict__ alphaS)
{
  const int b = blockIdx.x;
  const int tid = threadIdx.x;
  const bool is_fwd = tid < 256;
  const int lane = tid & 63;

  __shared__ __align__(16) float P[2][144];     // fwd message exp(a - M)
  __shared__ __align__(16) float AV[2][144];    // viterbi alpha
  __shared__ __align__(16) float redmF[2][4];   // per-fwd-wave max (dbuf)
  __shared__ float reds[4];
  __shared__ float vitm[8];
  __shared__ int   viti[8];

  int myto, h;
  if (is_fwd) { myto = tid >> 1; h = tid & 1; }
  else { int q = tid - 256; myto = q >> 2; h = q & 3; }

  // per-thread transition slice: E=exp(trans) for fwd, raw for vit
  float R[64];
  if (is_fwd) {
    const float4* tr = (const float4*)(trans + (size_t)myto * KK + h * 64);
#pragma unroll
    for (int c = 0; c < 16; ++c) {
      float4 v = tr[c];
      R[4*c+0]=__expf(v.x); R[4*c+1]=__expf(v.y);
      R[4*c+2]=__expf(v.z); R[4*c+3]=__expf(v.w);
    }
  } else {
    const float4* tr = (const float4*)(trans + (size_t)myto * KK + h * 32);
#pragma unroll
    for (int c = 0; c < 8; ++c) {
      float4 v = tr[c];
      R[4*c+0]=v.x; R[4*c+1]=v.y; R[4*c+2]=v.z; R[4*c+3]=v.w;
    }
  }

  if (is_fwd) { if (h == 0) P[0][paddr(myto)] = (myto==START_TAG)?1.0f:0.0f; }
  else        { if (h == 0) AV[0][paddr(myto)] = (myto==START_TAG)?0.0f:NEGV; }
  if (tid < 4) redmF[1][tid] = 0.0f;   // M_{-1} = max(init alpha) = 0
  __syncthreads();

  const float* fb = feats + (size_t)b * TT * KK + myto;
  uint8_t* bp = bptr + (size_t)b * TT * KK + myto;
  float* aS = alphaS + (size_t)b * TT * KK;

  float fcur = fb[0];
  float Mprev = 0.0f;          // scale of the P we consume
  float aCarry = 0.0f;
  int cur = 0;

  for (int t = 0; t < TT; ++t) {
    const int tn = (t + 1 < TT) ? t + 1 : t;
    float fnext = fb[(size_t)tn * KK];
    const int rd = (t + 1) & 1, wr = t & 1;

    if (is_fwd) {
      float4 rv = *(const float4*)&redmF[rd][0];
      float M1 = fmaxf(fmaxf(rv.x, rv.y), fmaxf(rv.z, rv.w));   // M_{t-1}
      const float* Pc = &P[cur][0];
      const int base = h * 72;
      float s0=0.f, s1=0.f, s2=0.f, s3=0.f;
#pragma unroll
      for (int c = 0; c < 16; ++c) {
        float4 p = *(const float4*)&Pc[base + (c>>3)*36 + (c&7)*4];
        s0 = fmaf(R[4*c+0], p.x, s0);
        s1 = fmaf(R[4*c+1], p.y, s1);
        s2 = fmaf(R[4*c+2], p.z, s2);
        s3 = fmaf(R[4*c+3], p.w, s3);
      }
      float s = (s0 + s1) + (s2 + s3);
      s = s + dppf<0xB1>(s, s);                 // pair merge (exact)
      float a;
      if (CHEAP) a = Mprev + __logf(s) + fcur;
      else       a = Mprev + logf(s) + fcur;
      float wm = wave_max63(a);
      if (lane == 63) redmF[wr][tid >> 6] = wm;
      float pv = CHEAP ? __expf(a - M1) : expf(a - M1);
      if (h == 0) P[cur ^ 1][paddr(myto)] = pv;
      Mprev = M1;
      aCarry = a;
    } else if (CHEAP) {
      // Viterbi values only: add+max, no index tracking
      const float* Ac = &AV[cur][0];
      const int base = h * 36;
      float4 p0 = *(const float4*)&Ac[base];
      float m0 = p0.x + R[0], m1 = p0.y + R[1];
      float m2 = p0.z + R[2], m3 = p0.w + R[3];
#pragma unroll
      for (int c = 1; c < 8; ++c) {
        float4 p = *(const float4*)&Ac[base + c*4];
        m0 = fmaxf(m0, p.x + R[4*c+0]);
        m1 = fmaxf(m1, p.y + R[4*c+1]);
        m2 = fmaxf(m2, p.z + R[4*c+2]);
        m3 = fmaxf(m3, p.w + R[4*c+3]);
      }
      float m = fmaxf(fmaxf(m0, m1), fmaxf(m2, m3));
      m = fmaxf(m, dppf<0xB1>(m, m));           // merge h pairs
      m = fmaxf(m, dppf<0x4E>(m, m));           // merge across quad
      float a = m + fcur;
      if (h == 0) {
        AV[cur ^ 1][paddr(myto)] = a;
        __builtin_nontemporal_store(a, &aS[(size_t)t * KK + myto]);
      }
      aCarry = a;
    } else {
      // R2-proven exact argmax path (fallback)
      const float* Ac = &AV[cur][0];
      const int base = h * 36;
      const int fb0 = h * 32;
      float4 p0 = *(const float4*)&Ac[base];
      float m0 = p0.x + R[0], m1 = p0.y + R[1], m2 = p0.z + R[2], m3 = p0.w + R[3];
      int i0 = fb0, i1 = fb0+1, i2 = fb0+2, i3 = fb0+3;
#pragma unroll
      for (int c = 1; c < 8; ++c) {
        float4 p = *(const float4*)&Ac[base + c*4];
        float v0 = p.x + R[4*c+0]; if (v0 > m0) { m0 = v0; i0 = fb0+4*c+0; }
        float v1 = p.y + R[4*c+1]; if (v1 > m1) { m1 = v1; i1 = fb0+4*c+1; }
        float v2 = p.z + R[4*c+2]; if (v2 > m2) { m2 = v2; i2 = fb0+4*c+2; }
        float v3 = p.w + R[4*c+3]; if (v3 > m3) { m3 = v3; i3 = fb0+4*c+3; }
      }
      float m = m0; int i = i0;
      if (m1 > m || (m1 == m && i1 < i)) { m = m1; i = i1; }
      if (m2 > m || (m2 == m && i2 < i)) { m = m2; i = i2; }
      if (m3 > m || (m3 == m && i3 < i)) { m = m3; i = i3; }
      { float mo = dppf<0xB1>(m, m); int io = dppi<0xB1>(i, i);
        if (mo > m || (mo == m && io < i)) { m = mo; i = io; } }
      { float mo = dppf<0x4E>(m, m); int io = dppi<0x4E>(i, i);
        if (mo > m || (mo == m && io < i)) { m = mo; i = io; } }
      float a = m + fcur;
      if (h == 0) { AV[cur ^ 1][paddr(myto)] = a; bp[(size_t)t * KK] = (uint8_t)i; }
      aCarry = a;
    }
    __syncthreads();
    cur ^= 1;
    fcur = fnext;
  }

  // ---- terminal reductions ----
  float tstop = trans[(size_t)STOP_TAG * KK + myto];
  float term = aCarry + tstop;
  float M = 0.0f;
  if (is_fwd) {
    float wm = wave_max63(term);
    if (lane == 63) redmF[0][tid >> 6] = wm;
  } else {
    float m = term; int i = myto;
#pragma unroll
    for (int off = 1; off < 64; off <<= 1) {
      float mo = __shfl_xor(m, off, 64);
      int   io = __shfl_xor(i, off, 64);
      if (mo > m || (mo == m && io < i)) { m = mo; i = io; }
    }
    if (lane == 0) { vitm[(tid>>6)-4] = m; viti[(tid>>6)-4] = i; }
  }
  __syncthreads();
  if (is_fwd) {
    float4 rv = *(const float4*)&redmF[0][0];
    M = fmaxf(fmaxf(rv.x, rv.y), fmaxf(rv.z, rv.w));
    float e = CHEAP ? __expf(term - M) : expf(term - M);
#pragma unroll
    for (int off = 1; off < 64; off <<= 1) e += __shfl_xor(e, off, 64);
    if (lane == 0) reds[tid >> 6] = e;
  } else if (tid == 256) {
    float m = vitm[0]; int i = viti[0];
#pragma unroll
    for (int w = 1; w < 8; ++w)
      if (vitm[w] > m || (vitm[w] == m && viti[w] < i)) { m = vitm[w]; i = viti[w]; }
    pscore[b] = m; lasttag[b] = i;
  }
  __syncthreads();
  if (tid == 0) {
    float sm = reds[0] + reds[1] + reds[2] + reds[3];
    logz[b] = M + (CHEAP ? __logf(sm) : logf(sm));
  }
}

// ---------------------------------------------------------------------------
// backtrace_alpha: per b, recompute argmax along surviving path from stored
// exact alpha rows. trans staged in LDS (64KB); alpha rows prefetched 8 deep
// (tag-independent addresses). Exact first-index tie rule via ballot+ctz.
// ---------------------------------------------------------------------------
__global__ __launch_bounds__(64) void backtrace_alpha(
    const float* __restrict__ alphaS, const float* __restrict__ trans,
    const int* __restrict__ lasttag, float* __restrict__ pred)
{
  const int b = blockIdx.x;
  const int lane = threadIdx.x;
  __shared__ float tl[KK * KK];                 // 64 KB
  {
    const float4* src = (const float4*)trans;
    float4* dst = (float4*)tl;
#pragma unroll
    for (int i = 0; i < (KK * KK / 4) / 64; ++i) dst[lane + i * 64] = src[lane + i * 64];
  }
  int tag = lasttag[b];
  if (lane == 0) pred[(size_t)b * TT + (TT - 1)] = (float)tag;
  const float* arow = alphaS + (size_t)b * TT * KK;

  float p0[8], p1[8];
#pragma unroll
  for (int j = 0; j < 8; ++j) {
    int r = TT - 2 - j;
    p0[j] = arow[(size_t)r * KK + lane];
    p1[j] = arow[(size_t)r * KK + 64 + lane];
  }
  __syncthreads();

  for (int rb = TT - 2; rb >= 0; rb -= 8) {
#pragma unroll
    for (int j = 0; j < 8; ++j) {
      int r = rb - j;
      if (r >= 0) {
        float x0 = p0[j] + tl[tag * KK + lane];
        float x1 = p1[j] + tl[tag * KK + 64 + lane];
        float m = fmaxf(x0, x1);
        float M = wave_max63(m);
        M = __int_as_float(__builtin_amdgcn_readlane(__float_as_int(M), 63));
        unsigned long long b0 = __ballot(x0 == M);
        unsigned long long b1 = __ballot(x1 == M);
        tag = b0 ? (int)__builtin_ctzll(b0) : 64 + (int)__builtin_ctzll(b1);
        if (lane == 0) pred[(size_t)b * TT + r] = (float)tag;
        int rp = r - 8;
        if (rp >= 0) {
          p0[j] = arow[(size_t)rp * KK + lane];
          p1[j] = arow[(size_t)rp * KK + 64 + lane];
        }
      }
    }
  }
}

// ---------------------------------------------------------------------------
// Fallback backtrace over stored bptr bytes (R2-proven).
// ---------------------------------------------------------------------------
__global__ __launch_bounds__(256) void backtrace_kernel(
    const uint8_t* __restrict__ bptr, const int* __restrict__ lasttag,
    float* __restrict__ pred)
{
  const int b = blockIdx.x;
  const int tid = threadIdx.x;
  __shared__ __align__(16) uint8_t lb[(TT / 2) * KK];
  __shared__ int tagcarry;
  if (tid == 0) tagcarry = lasttag[b];

  for (int half = 1; half >= 0; --half) {
    __syncthreads();
    const float4* src = reinterpret_cast<const float4*>(
        bptr + ((size_t)b * TT + (size_t)half * (TT / 2)) * KK);
    float4* dst = reinterpret_cast<float4*>(lb);
    for (int i = tid; i < (TT / 2) * KK / 16; i += 256) dst[i] = src[i];
    __syncthreads();
    if (tid == 0) {
      int tag = tagcarry;
      for (int t = TT / 2 - 1; t >= 0; --t) {
        int gt = half * (TT / 2) + t;
        pred[(size_t)b * TT + gt] = (float)tag;
        tag = lb[t * KK + tag];
      }
      tagcarry = tag;
    }
  }
}

// ---------------------------------------------------------------------------
__global__ __launch_bounds__(64) void gold_kernel(
    const float* __restrict__ feats, const int* __restrict__ tags,
    const float* __restrict__ trans, const float* __restrict__ logz,
    float* __restrict__ gb)
{
  const int b = blockIdx.x;
  const int lane = threadIdx.x;
  const int* tg = tags + (size_t)b * TT;
  const float* fb = feats + (size_t)b * TT * KK;
  float g = 0.0f;
#pragma unroll
  for (int k = 0; k < TT / 64; ++k) {
    int t = lane * (TT / 64) + k;
    int ct = tg[t];
    int pv = (t == 0) ? START_TAG : tg[t - 1];
    g += trans[ct * KK + pv] + fb[(size_t)t * KK + ct];
  }
  if (lane == 63) g += trans[STOP_TAG * KK + tg[TT - 1]];
#pragma unroll
  for (int off = 1; off <= 32; off <<= 1) g += __shfl_xor(g, off, 64);
  if (lane == 0) gb[b] = logz[b] - g;
}

__global__ __launch_bounds__(256) void loss_reduce(
    const float* __restrict__ gb, float* __restrict__ out)
{
  const int tid = threadIdx.x;
  const int lane = tid & 63, wv = tid >> 6;
  float v = gb[tid];
#pragma unroll
  for (int off = 1; off <= 32; off <<= 1) v += __shfl_xor(v, off, 64);
  __shared__ float red[4];
  if (lane == 0) red[wv] = v;
  __syncthreads();
  if (tid == 0) out[0] = (red[0] + red[1] + red[2] + red[3]) / (float)(BB * TT);
}

// ---------------------------------------------------------------------------
extern "C" void kernel_launch(void* const* d_in, const int* in_sizes, int n_in,
                              void* d_out, int out_size, void* d_ws, size_t ws_size,
                              hipStream_t stream) {
  const float* feats = (const float*)d_in[0];
  const int*   tags  = (const int*)d_in[1];
  const float* trans = (const float*)d_in[2];

  float* out    = (float*)d_out;
  float* loss   = out;
  float* pscore = out + 1;
  float* pred   = out + 1 + BB;
  (void)in_sizes; (void)n_in; (void)out_size;

  const size_t alpha_bytes = (size_t)BB * TT * KK * sizeof(float);   // 64 MB
  const bool cheap = ws_size >= alpha_bytes + 4096;

  if (cheap) {
    float* alphaS  = (float*)d_ws;
    char*  wsend   = (char*)d_ws + alpha_bytes;
    float* logz    = (float*)(wsend);
    int*   lasttag = (int*)(wsend + BB * sizeof(float));
    float* gb      = (float*)(wsend + BB * sizeof(float) + BB * sizeof(int));
    crf_main<true><<<BB, 768, 0, stream>>>(feats, trans, logz, pscore, lasttag,
                                           (uint8_t*)nullptr, alphaS);
    backtrace_alpha<<<BB, 64, 0, stream>>>(alphaS, trans, lasttag, pred);
    gold_kernel<<<BB, 64, 0, stream>>>(feats, tags, trans, logz, gb);
    loss_reduce<<<1, 256, 0, stream>>>(gb, loss);
  } else {
    uint8_t* bptr    = (uint8_t*)d_ws;
    char*    wsend   = (char*)d_ws + (size_t)BB * TT * KK;
    float*   logz    = (float*)(wsend);
    int*     lasttag = (int*)(wsend + BB * sizeof(float));
    float*   gb      = (float*)(wsend + BB * sizeof(float) + BB * sizeof(int));
    crf_main<false><<<BB, 768, 0, stream>>>(feats, trans, logz, pscore, lasttag,
                                            bptr, (float*)nullptr);
    backtrace_kernel<<<BB, 256, 0, stream>>>(bptr, lasttag, pred);
    gold_kernel<<<BB, 64, 0, stream>>>(feats, tags, trans, logz, gb);
    loss_reduce<<<1, 256, 0, stream>>>(gb, loss);
  }
}